// Round 20
// baseline (650.594 us; speedup 1.0000x reference)
//
#include <hip/hip_runtime.h>
#include <hip/hip_bf16.h>
#include <math.h>

#define N0 100000
#define E0 600000
#define KP1 80000
#define KP2 64000
#define KP3 51200
#define F 128
#define SCAN_CHUNK 1024
#define NCHUNK ((N0 + SCAN_CHUNK - 1) / SCAN_CHUNK)
#define MAXGB 6400
#define NBCVT 12500                 // ceil(N0*F/4 / 256)
#define NBW 96                      // 16 x 6 weight-convert blocks
#define NBHD ((E0 + 255) / 256)

typedef __attribute__((ext_vector_type(8))) short short8;
typedef __attribute__((ext_vector_type(8))) unsigned short ushort8;
typedef __attribute__((ext_vector_type(4))) float f32x4;

// ---------- helpers ----------
__device__ __forceinline__ unsigned fkey(float f) {
    unsigned u = __float_as_uint(f);
    return u ^ ((u & 0x80000000u) ? 0xFFFFFFFFu : 0x80000000u);
}
__device__ __forceinline__ unsigned short f2b(float f) {
    __hip_bfloat16 h = __float2bfloat16(f);
    return *(unsigned short*)&h;
}
__device__ __forceinline__ float b2f(unsigned short u) {
    __hip_bfloat16 h;
    *(unsigned short*)&h = u;
    return __bfloat162float(h);
}

// ---------- fused setup: x->bf16 (+zero bar/hist/cnt, iota), W->bf16, pwn ----------
__global__ __launch_bounds__(256) void setupK(const float* __restrict__ x, unsigned short* __restrict__ xbf,
                                              const float* __restrict__ a0, const float* __restrict__ a1,
                                              const float* __restrict__ a2, const float* __restrict__ a3,
                                              const float* __restrict__ a4, const float* __restrict__ a5,
                                              unsigned short* __restrict__ wbf,
                                              const float* __restrict__ p0, const float* __restrict__ p1,
                                              const float* __restrict__ p2, float* __restrict__ pwn,
                                              unsigned* __restrict__ cnt, int* __restrict__ orig,
                                              unsigned* __restrict__ bar, unsigned* __restrict__ hist) {
    __shared__ float shf[128];
    int b = blockIdx.x, tid = threadIdx.x;
    if (b < NBCVT) {
        if (b == 0) {
            if (tid < 16) bar[tid] = 0u;
            hist[tid] = 0u;
        }
        int i = b * 256 + tid;
        if (i < N0) { cnt[i] = 0u; orig[i] = i; }
        if (i < N0 * F / 4) {
            float4 v = *(const float4*)(x + (size_t)i * 4);
            *(ushort4*)(xbf + (size_t)i * 4) = make_ushort4(f2b(v.x), f2b(v.y), f2b(v.z), f2b(v.w));
        }
    } else if (b < NBCVT + NBW) {
        int bb = b - NBCVT;
        int m = bb >> 4;
        const float* src = (m == 0) ? a0 : (m == 1) ? a1 : (m == 2) ? a2 : (m == 3) ? a3 : (m == 4) ? a4 : a5;
        int i = (bb & 15) * 256 + tid;
        float4 v = *(const float4*)(src + (size_t)i * 4);
        *(ushort4*)(wbf + (size_t)m * 16384 + (size_t)i * 4) = make_ushort4(f2b(v.x), f2b(v.y), f2b(v.z), f2b(v.w));
    } else {
        // pwn: 3 layers sequential in one block
        for (int l = 0; l < 3; l++) {
            const float* p = (l == 0) ? p0 : (l == 1) ? p1 : p2;
            float v = 0.f;
            if (tid < 128) { v = p[tid]; shf[tid] = v * v; }
            __syncthreads();
            for (int off = 64; off; off >>= 1) {
                if (tid < off) shf[tid] += shf[tid + off];
                __syncthreads();
            }
            float nrm = sqrtf(shf[0]);
            __syncthreads();
            if (tid < 128) pwn[l * 128 + tid] = v / nrm;
            __syncthreads();
        }
    }
}

// ---------- CSR build ----------
__global__ __launch_bounds__(256) void histDstK(const int* __restrict__ dst, unsigned* __restrict__ cnt) {
    int e = blockIdx.x * 256 + threadIdx.x;
    if (e < E0) atomicAdd(&cnt[dst[e]], 1u);
}

// scanReduce + fused serial chunk scan (last-block-done, proven R16)
__global__ __launch_bounds__(256) void scanRedFusedK(const unsigned* __restrict__ cnt,
                                                     unsigned* __restrict__ chunkSum,
                                                     unsigned* __restrict__ chunkOff,
                                                     unsigned* __restrict__ rowptr,
                                                     unsigned* __restrict__ done, int nbins) {
    __shared__ unsigned sh[256];
    __shared__ bool last;
    int tid = threadIdx.x;
    int base = blockIdx.x * SCAN_CHUNK + tid * 4;
    unsigned s = 0;
#pragma unroll
    for (int i = 0; i < 4; i++) { int b = base + i; if (b < nbins) s += cnt[b]; }
    sh[tid] = s;
    __syncthreads();
    for (int off = 128; off; off >>= 1) {
        if (tid < off) sh[tid] += sh[tid + off];
        __syncthreads();
    }
    if (tid == 0) {
        atomicExch(&chunkSum[blockIdx.x], sh[0]);
        __threadfence();
        last = (atomicAdd(done, 1u) == (unsigned)(NCHUNK - 1));
    }
    __syncthreads();
    if (!last) return;
    if (tid == 0) {
        unsigned run = 0;
        for (int i = 0; i < NCHUNK; i++) {
            atomicExch(&chunkOff[i], run);
            run += atomicAdd(&chunkSum[i], 0u);
        }
        rowptr[N0] = run;
        *done = 0u;
    }
}

__global__ __launch_bounds__(256) void scanFinalK(const unsigned* __restrict__ cntIn,
                                                  unsigned* __restrict__ cnt,
                                                  const unsigned* __restrict__ chunkOff,
                                                  unsigned* __restrict__ rowptr, int nbins) {
    __shared__ unsigned sh[256];
    int t = threadIdx.x;
    int base = blockIdx.x * SCAN_CHUNK + t * 4;
    unsigned c[4], s = 0;
#pragma unroll
    for (int i = 0; i < 4; i++) { int b = base + i; c[i] = (b < nbins) ? cntIn[b] : 0u; s += c[i]; }
    sh[t] = s;
    __syncthreads();
    for (int off = 1; off < 256; off <<= 1) {
        unsigned v = (t >= off) ? sh[t - off] : 0u;
        __syncthreads();
        sh[t] += v;
        __syncthreads();
    }
    unsigned basep = atomicAdd((unsigned*)&chunkOff[blockIdx.x], 0u) + sh[t] - s;
#pragma unroll
    for (int i = 0; i < 4; i++) {
        int b = base + i;
        if (b < nbins) { rowptr[b] = basep; basep += c[i]; cnt[b] = 0u; }
    }
}

__global__ __launch_bounds__(256) void scatterFillK(const int* __restrict__ src,
                                                    const int* __restrict__ dst,
                                                    const unsigned* __restrict__ rowptr,
                                                    unsigned* __restrict__ fill,
                                                    int* __restrict__ sortedSrc) {
    int e = blockIdx.x * 256 + threadIdx.x;
    if (e >= E0) return;
    int d = dst[e];
    unsigned p = rowptr[d] + atomicAdd(&fill[d], 1u);
    sortedSrc[p] = src[e];
}

// ---------- segmented aggregation (proven R7) ----------
__global__ __launch_bounds__(256) void aggSegB(const unsigned short* __restrict__ x,
                                               const int* __restrict__ srcCur,
                                               const unsigned* __restrict__ rowptr,
                                               const int* __restrict__ orig,
                                               unsigned short* __restrict__ agg, int n) {
    int g = blockIdx.x * 16 + (threadIdx.x >> 4);
    int q = threadIdx.x & 15;
    if (g >= n) return;
    int d = orig[g];
    unsigned e0 = rowptr[d], e1 = rowptr[d + 1];
    float a[8];
#pragma unroll
    for (int j = 0; j < 8; j++) a[j] = 0.f;
    unsigned e = e0;
    for (; e + 4 <= e1; e += 4) {
        int s0 = srcCur[e], s1 = srcCur[e + 1], s2 = srcCur[e + 2], s3 = srcCur[e + 3];
        ushort8 v0 = *(const ushort8*)(x + (size_t)(s0 < 0 ? 0 : s0) * F + q * 8);
        ushort8 v1 = *(const ushort8*)(x + (size_t)(s1 < 0 ? 0 : s1) * F + q * 8);
        ushort8 v2 = *(const ushort8*)(x + (size_t)(s2 < 0 ? 0 : s2) * F + q * 8);
        ushort8 v3 = *(const ushort8*)(x + (size_t)(s3 < 0 ? 0 : s3) * F + q * 8);
        float m0 = s0 < 0 ? 0.f : 1.f, m1 = s1 < 0 ? 0.f : 1.f;
        float m2 = s2 < 0 ? 0.f : 1.f, m3 = s3 < 0 ? 0.f : 1.f;
#pragma unroll
        for (int j = 0; j < 8; j++) {
            a[j] = fmaf(b2f(v0[j]), m0, a[j]);
            a[j] = fmaf(b2f(v1[j]), m1, a[j]);
            a[j] = fmaf(b2f(v2[j]), m2, a[j]);
            a[j] = fmaf(b2f(v3[j]), m3, a[j]);
        }
    }
    for (; e < e1; e++) {
        int s = srcCur[e];
        if (s < 0) continue;
        ushort8 v = *(const ushort8*)(x + (size_t)s * F + q * 8);
#pragma unroll
        for (int j = 0; j < 8; j++) a[j] += b2f(v[j]);
    }
    ushort8 o;
#pragma unroll
    for (int j = 0; j < 8; j++) o[j] = f2b(a[j]);
    *(ushort8*)(agg + (size_t)g * F + q * 8) = o;
}

// ---------- MFMA conv + score + fused radix pass 0 ----------
// R20: R12/R15 structure + register prefetch of the next kk slice (single change).
#define CPAD 40
__global__ __launch_bounds__(256) void convM(const unsigned short* __restrict__ A0,
                                             const unsigned short* __restrict__ A1,
                                             const unsigned short* __restrict__ W0,
                                             const unsigned short* __restrict__ W1,
                                             const float* __restrict__ br,
                                             const float* __restrict__ pwn,
                                             unsigned short* __restrict__ hbf,
                                             float* __restrict__ sc,
                                             unsigned* __restrict__ keys,
                                             unsigned* __restrict__ hist,
                                             unsigned* __restrict__ st,
                                             unsigned* __restrict__ done,
                                             int n, int k, int nbGrid) {
    __shared__ unsigned short As[128 * CPAD];
    __shared__ unsigned short Bs[128 * CPAD];
    __shared__ unsigned selh[256];
    int tid = threadIdx.x;
    int w = tid >> 6, l = tid & 63;
    int r = l & 15, g = l >> 4;
    int bm = blockIdx.x * 128;
    int srow = tid >> 2, q4 = tid & 3;

    selh[tid] = 0u;

    f32x4 acc[2][8];
#pragma unroll
    for (int m = 0; m < 2; m++)
#pragma unroll
        for (int c = 0; c < 8; c++) acc[m][c] = (f32x4){0.f, 0.f, 0.f, 0.f};

    // software pipeline: preload slice 0 into registers
    uint4 avP[2], wvP[2];
#pragma unroll
    for (int h2 = 0; h2 < 2; h2++) {
        int rr = srow + h2 * 64;
        avP[h2] = make_uint4(0u, 0u, 0u, 0u);
        if (bm + rr < n) avP[h2] = *(const uint4*)(A0 + (size_t)(bm + rr) * F + q4 * 8);
        wvP[h2] = *(const uint4*)(W0 + (size_t)rr * F + q4 * 8);
    }

    for (int it = 0; it < 8; it++) {
        __syncthreads();    // prior readers of As/Bs done
#pragma unroll
        for (int h2 = 0; h2 < 2; h2++) {
            int rr = srow + h2 * 64;
            *(uint4*)(&As[rr * CPAD + q4 * 8]) = avP[h2];
            *(uint4*)(&Bs[rr * CPAD + q4 * 8]) = wvP[h2];
        }
        if (it < 7) {       // issue next slice's loads; they fly under the MFMA below
            int it2 = it + 1;
            const unsigned short* A = (it2 >= 4) ? A1 : A0;
            const unsigned short* W = (it2 >= 4) ? W1 : W0;
            int kk2 = (it2 & 3) * 32;
#pragma unroll
            for (int h2 = 0; h2 < 2; h2++) {
                int rr = srow + h2 * 64;
                avP[h2] = make_uint4(0u, 0u, 0u, 0u);
                if (bm + rr < n) avP[h2] = *(const uint4*)(A + (size_t)(bm + rr) * F + kk2 + q4 * 8);
                wvP[h2] = *(const uint4*)(W + (size_t)rr * F + kk2 + q4 * 8);
            }
        }
        __syncthreads();    // LDS visible
        short8 af[2], bf[8];
#pragma unroll
        for (int m = 0; m < 2; m++)
            af[m] = *(const short8*)(&As[(w * 32 + m * 16 + r) * CPAD + g * 8]);
#pragma unroll
        for (int c = 0; c < 8; c++)
            bf[c] = *(const short8*)(&Bs[(c * 16 + r) * CPAD + g * 8]);
#pragma unroll
        for (int m = 0; m < 2; m++)
#pragma unroll
            for (int c = 0; c < 8; c++)
                acc[m][c] = __builtin_amdgcn_mfma_f32_16x16x32_bf16(af[m], bf[c], acc[m][c], 0, 0, 0);
    }

    float pd[2][4];
#pragma unroll
    for (int m = 0; m < 2; m++)
#pragma unroll
        for (int j = 0; j < 4; j++) pd[m][j] = 0.f;

#pragma unroll
    for (int c = 0; c < 8; c++) {
        int col = c * 16 + r;
        float bias = br[col];
        float pwc = pwn[col];
#pragma unroll
        for (int m = 0; m < 2; m++) {
#pragma unroll
            for (int j = 0; j < 4; j++) {
                int row = bm + w * 32 + m * 16 + g * 4 + j;
                float h = fmaxf(acc[m][c][j] + bias, 0.f);
                pd[m][j] += h * pwc;
                if (row < n) hbf[(size_t)row * F + col] = f2b(h);
            }
        }
    }
#pragma unroll
    for (int m = 0; m < 2; m++) {
#pragma unroll
        for (int j = 0; j < 4; j++) {
            float p = pd[m][j];
            p += __shfl_xor(p, 1);
            p += __shfl_xor(p, 2);
            p += __shfl_xor(p, 4);
            p += __shfl_xor(p, 8);
            if (r == 0) {
                int row = bm + w * 32 + m * 16 + g * 4 + j;
                if (row < n) {
                    float s = tanhf(p);
                    sc[row] = s;
                    unsigned key = fkey(s);
                    keys[row] = key;
                    atomicAdd(&selh[key >> 24], 1u);
                }
            }
        }
    }

    __syncthreads();
    if (selh[tid]) atomicAdd(&hist[tid], selh[tid]);
    __syncthreads();
    __shared__ bool lastS;
    if (tid == 0) {
        __threadfence();
        lastS = (atomicAdd(done, 1u) == (unsigned)(nbGrid - 1));
    }
    __syncthreads();
    if (!lastS) return;
    selh[tid] = atomicExch(&hist[tid], 0u);
    __syncthreads();
    if (tid == 0) {
        unsigned krem = (unsigned)k, cum = 0, pfx = 0;
        for (int bch = 255; bch >= 0; bch--) {
            unsigned cc = selh[bch];
            if (cum + cc >= krem) {
                pfx = ((unsigned)bch) << 24;
                krem -= cum;
                break;
            }
            cum += cc;
        }
        atomicExch(&st[0], pfx);
        atomicExch(&st[1], krem);
        *done = 0u;
    }
}

// ---------- radix passes 1..3 (proven R7/R15) ----------
__global__ __launch_bounds__(256) void histSelK(const unsigned* __restrict__ keys, int n,
                                                int p, unsigned* __restrict__ st,
                                                unsigned* __restrict__ hist,
                                                unsigned* __restrict__ done, int nb) {
    __shared__ unsigned lh[256];
    __shared__ bool last;
    int tid = threadIdx.x;
    lh[tid] = 0;
    __syncthreads();
    unsigned prefix = st[0];
    int i = blockIdx.x * 256 + tid;
    if (i < n) {
        unsigned key = keys[i];
        bool m = ((key >> (32 - 8 * p)) == (prefix >> (32 - 8 * p)));
        if (m) atomicAdd(&lh[(key >> (24 - 8 * p)) & 255u], 1u);
    }
    __syncthreads();
    if (lh[tid]) atomicAdd(&hist[tid], lh[tid]);
    __syncthreads();
    if (tid == 0) {
        __threadfence();
        last = (atomicAdd(done, 1u) == (unsigned)(nb - 1));
    }
    __syncthreads();
    if (!last) return;
    lh[tid] = atomicExch(&hist[tid], 0u);
    __syncthreads();
    if (tid == 0) {
        unsigned krem = st[1], cum = 0;
        for (int b = 255; b >= 0; b--) {
            unsigned c = lh[b];
            if (cum + c >= krem) {
                st[0] |= ((unsigned)b) << (24 - 8 * p);
                st[1] = krem - cum;
                break;
            }
            cum += c;
        }
        *done = 0u;
    }
}

// ---------- counts + fused scan (proven R13/R15) ----------
__global__ __launch_bounds__(256) void countsK(const unsigned* __restrict__ keys, int n,
                                               const unsigned* __restrict__ st,
                                               unsigned* __restrict__ bGT, unsigned* __restrict__ bEQ,
                                               unsigned* __restrict__ sGT, unsigned* __restrict__ sEQ,
                                               unsigned* __restrict__ done, int nb) {
    __shared__ int cg_, ce_;
    __shared__ bool last;
    __shared__ unsigned sgl[128], seq[128];
    int tid = threadIdx.x;
    if (tid == 0) { cg_ = 0; ce_ = 0; }
    __syncthreads();
    unsigned t = st[0];
    int g = 0, e = 0;
    for (int it = 0; it < 4; it++) {
        int i = blockIdx.x * 1024 + it * 256 + tid;
        if (i < n) {
            unsigned k = keys[i];
            g += (k > t);
            e += (k == t);
        }
    }
    atomicAdd(&cg_, g);
    atomicAdd(&ce_, e);
    __syncthreads();
    if (tid == 0) {
        bGT[blockIdx.x] = (unsigned)cg_;
        bEQ[blockIdx.x] = (unsigned)ce_;
        __threadfence();
        last = (atomicAdd(done, 1u) == (unsigned)(nb - 1));
    }
    __syncthreads();
    if (!last) return;
    if (tid < nb && tid < 128) { sgl[tid] = atomicAdd(&bGT[tid], 0u); seq[tid] = atomicAdd(&bEQ[tid], 0u); }
    __syncthreads();
    if (tid == 0) {
        unsigned gs = 0, es = 0;
        for (int b = 0; b < nb; b++) {
            atomicExch(&sGT[b], gs);
            atomicExch(&sEQ[b], es);
            gs += sgl[b];
            es += seq[b];
        }
        *done = 0u;
    }
}

// ---------- mark + buildOrig (proven R8/R11/R15) ----------
__global__ __launch_bounds__(256) void markOrigK(const unsigned* __restrict__ keys, int n,
                                                 const unsigned* __restrict__ st,
                                                 const unsigned* __restrict__ sGT,
                                                 const unsigned* __restrict__ sEQ,
                                                 int* __restrict__ nidx,
                                                 const int* __restrict__ origIn,
                                                 int* __restrict__ origOut, int doNext) {
    __shared__ int wG[4], wE[4];
    __shared__ int runG, runE;
    int tid = threadIdx.x, wv = tid >> 6, lane = tid & 63;
    if (tid == 0) { runG = 0; runE = 0; }
    unsigned t = st[0];
    int needEq = (int)st[1];
    int gOff = (int)atomicAdd((unsigned*)&sGT[blockIdx.x], 0u);
    int eOff = (int)atomicAdd((unsigned*)&sEQ[blockIdx.x], 0u);
    unsigned long long mlt = (((unsigned long long)1) << lane) - 1ull;
    __syncthreads();
    for (int it = 0; it < 4; it++) {
        int i = blockIdx.x * 1024 + it * 256 + tid;
        bool inb = i < n;
        unsigned k = inb ? keys[i] : 0u;
        bool pG = inb && (k > t), pE = inb && (k == t);
        unsigned long long bG = __ballot(pG), bE = __ballot(pE);
        int lpG = __popcll(bG & mlt), lpE = __popcll(bE & mlt);
        if (lane == 0) { wG[wv] = __popcll(bG); wE[wv] = __popcll(bE); }
        __syncthreads();
        int woG = 0, woE = 0;
        for (int w = 0; w < wv; w++) { woG += wG[w]; woE += wE[w]; }
        int gB = gOff + runG + woG + lpG;
        int eB = eOff + runE + woE + lpE;
        int ni = -1;
        if (pG) ni = gB + (eB < needEq ? eB : needEq);
        else if (pE && eB < needEq) ni = gB + eB;
        if (inb) {
            nidx[i] = ni;
            if (doNext && ni >= 0) origOut[ni] = origIn[i];
        }
        __syncthreads();
        if (tid == 0) {
            runG += wG[0] + wG[1] + wG[2] + wG[3];
            runE += wE[0] + wE[1] + wE[2] + wE[3];
        }
        __syncthreads();
    }
}

// ---------- gather + remap + readout partials (proven R11) ----------
__global__ __launch_bounds__(256) void gatherRK(const unsigned short* __restrict__ hbf,
                                                const float* __restrict__ sc,
                                                const int* __restrict__ nidx,
                                                const int* __restrict__ srcIn,
                                                int* __restrict__ srcOut,
                                                unsigned short* __restrict__ bufB,
                                                float* __restrict__ pmax, float* __restrict__ psum,
                                                int n, int doNext) {
    __shared__ float redm[256 * 8];
    __shared__ float reds[256 * 8];
    int tid = threadIdx.x, b = blockIdx.x;
    int q = tid & 15;
    int i = b * 16 + (tid >> 4);
    float lm[8], ls[8];
#pragma unroll
    for (int j = 0; j < 8; j++) { lm[j] = -INFINITY; ls[j] = 0.f; }
    if (i < n) {
        int ni = nidx[i];
        if (ni >= 0) {
            float s = sc[i];
            ushort8 v = *(const ushort8*)(hbf + (size_t)i * F + q * 8);
            ushort8 o;
#pragma unroll
            for (int j = 0; j < 8; j++) {
                float prod = b2f(v[j]) * s;
                o[j] = f2b(prod);
                lm[j] = fmaxf(lm[j], prod);
                ls[j] += prod;
            }
            *(ushort8*)(bufB + (size_t)ni * F + q * 8) = o;
        }
    }
    if (doNext) {
        int nbg = gridDim.x;
        for (int e = b * 256 + tid; e < E0; e += nbg * 256) {
            int s2 = srcIn[e];
            srcOut[e] = (s2 >= 0) ? nidx[s2] : -1;
        }
    }
#pragma unroll
    for (int j = 0; j < 8; j++) { redm[tid * 8 + j] = lm[j]; reds[tid * 8 + j] = ls[j]; }
    __syncthreads();
    if (tid < 16) {
        for (int g2 = 1; g2 < 16; g2++) {
#pragma unroll
            for (int j = 0; j < 8; j++) {
                lm[j] = fmaxf(lm[j], redm[(g2 * 16 + tid) * 8 + j]);
                ls[j] += reds[(g2 * 16 + tid) * 8 + j];
            }
        }
#pragma unroll
        for (int j = 0; j < 8; j++) {
            pmax[(size_t)b * 128 + tid * 8 + j] = lm[j];
            psum[(size_t)b * 128 + tid * 8 + j] = ls[j];
        }
    }
}

// ---------- 2-stage readout final (proven R11/R13) ----------
__global__ __launch_bounds__(128) void rfinal2K(const float* __restrict__ pmax,
                                                const float* __restrict__ psum,
                                                unsigned* __restrict__ pm2, unsigned* __restrict__ ps2,
                                                float* __restrict__ r, unsigned* __restrict__ done,
                                                int np, int k, int initR) {
    int t = threadIdx.x, b = blockIdx.x;
    float m = -INFINITY, s = 0.f;
    for (int row = b; row < np; row += 64) {
        m = fmaxf(m, pmax[(size_t)row * 128 + t]);
        s += psum[(size_t)row * 128 + t];
    }
    atomicExch(&pm2[b * 128 + t], __float_as_uint(m));
    atomicExch(&ps2[b * 128 + t], __float_as_uint(s));
    __syncthreads();
    __shared__ bool last;
    if (t == 0) {
        __threadfence();
        last = (atomicAdd(done, 1u) == 63u);
    }
    __syncthreads();
    if (!last) return;
    m = -INFINITY; s = 0.f;
#pragma unroll 8
    for (int bb = 0; bb < 64; bb++) {
        m = fmaxf(m, __uint_as_float(atomicAdd(&pm2[bb * 128 + t], 0u)));
        s += __uint_as_float(atomicAdd(&ps2[bb * 128 + t], 0u));
    }
    if (initR) { r[t] = m; r[128 + t] = s / (float)k; }
    else       { r[t] += m; r[128 + t] += s / (float)k; }
    if (t == 0) *done = 0u;
}

// ---------- final MLP ----------
__global__ __launch_bounds__(256) void mlpK(const float* __restrict__ r,
                                            const float* __restrict__ W1, const float* __restrict__ b1,
                                            const float* __restrict__ W2, const float* __restrict__ b2,
                                            const float* __restrict__ W3, const float* __restrict__ b3,
                                            float* __restrict__ out) {
    __shared__ float z0[256], z1[128], z2[64];
    int t = threadIdx.x;
    z0[t] = r[t];
    __syncthreads();
    if (t < 128) {
        float a = b1[t];
        for (int kk = 0; kk < 256; kk++) a = fmaf(W1[t * 256 + kk], z0[kk], a);
        z1[t] = fmaxf(a, 0.f);
    }
    __syncthreads();
    if (t < 64) {
        float a = b2[t];
        for (int kk = 0; kk < 128; kk++) a = fmaf(W2[t * 128 + kk], z1[kk], a);
        z2[t] = fmaxf(a, 0.f);
    }
    __syncthreads();
    if (t < 2) {
        float a = b3[t];
        for (int kk = 0; kk < 64; kk++) a = fmaf(W3[t * 64 + kk], z2[kk], a);
        out[t] = a;
    }
}

extern "C" void kernel_launch(void* const* d_in, const int* in_sizes, int n_in,
                              void* d_out, int out_size, void* d_ws, size_t ws_size,
                              hipStream_t stream) {
    const float* x = (const float*)d_in[0];
    const int* ei = (const int*)d_in[1];
    const float* Wr[3]    = { (const float*)d_in[2],  (const float*)d_in[6],  (const float*)d_in[10] };
    const float* br[3]    = { (const float*)d_in[3],  (const float*)d_in[7],  (const float*)d_in[11] };
    const float* Wroot[3] = { (const float*)d_in[4],  (const float*)d_in[8],  (const float*)d_in[12] };
    const float* pw[3]    = { (const float*)d_in[5],  (const float*)d_in[9],  (const float*)d_in[13] };
    const float* W1 = (const float*)d_in[14];
    const float* b1 = (const float*)d_in[15];
    const float* W2 = (const float*)d_in[16];
    const float* b2 = (const float*)d_in[17];
    const float* W3 = (const float*)d_in[18];
    const float* b3 = (const float*)d_in[19];
    float* out = (float*)d_out;
    char* w = (char*)d_ws;

    size_t o = 0;
    auto alc = [&](size_t bytes) { size_t r = o; o += (bytes + 255) & ~(size_t)255; return r; };
    unsigned short* hbf    = (unsigned short*)(w + alc((size_t)N0 * F * 2));
    unsigned short* xbf    = (unsigned short*)(w + alc((size_t)N0 * F * 2));
    unsigned short* aggbf  = (unsigned short*)(w + alc((size_t)N0 * F * 2));
    unsigned short* bufBbf = (unsigned short*)(w + alc((size_t)KP1 * F * 2));
    unsigned short* wbf    = (unsigned short*)(w + alc((size_t)6 * 16384 * 2));
    float*    pwn    = (float*)(w + alc(3 * 128 * 4));
    float*    sc     = (float*)(w + alc((size_t)N0 * 4));
    unsigned* keys   = (unsigned*)(w + alc((size_t)N0 * 4));
    int*      nidx   = (int*)(w + alc((size_t)N0 * 4));
    int*      sSrc0  = (int*)(w + alc((size_t)E0 * 4));
    int*      srcCA  = (int*)(w + alc((size_t)E0 * 4));
    int*      srcCB  = (int*)(w + alc((size_t)E0 * 4));
    unsigned* cnt    = (unsigned*)(w + alc((size_t)N0 * 4));
    unsigned* rowptr = (unsigned*)(w + alc((size_t)(N0 + 1) * 4));
    int*      origA  = (int*)(w + alc((size_t)N0 * 4));
    int*      origB  = (int*)(w + alc((size_t)N0 * 4));
    unsigned* chS    = (unsigned*)(w + alc(NCHUNK * 4));
    unsigned* chO    = (unsigned*)(w + alc(NCHUNK * 4));
    unsigned* hist   = (unsigned*)(w + alc(256 * 4));
    unsigned* st     = (unsigned*)(w + alc(64));
    unsigned* barA   = (unsigned*)(w + alc(16 * 4));
    unsigned* bGT    = (unsigned*)(w + alc(128 * 4));
    unsigned* bEQ    = (unsigned*)(w + alc(128 * 4));
    unsigned* sGT    = (unsigned*)(w + alc(128 * 4));
    unsigned* sEQ    = (unsigned*)(w + alc(128 * 4));
    float*    r      = (float*)(w + alc(256 * 4));
    float*    pmax   = (float*)(w + alc((size_t)MAXGB * F * 4));
    float*    psum   = (float*)(w + alc((size_t)MAXGB * F * 4));
    unsigned* pm2    = (unsigned*)(w + alc(64 * 128 * 4));
    unsigned* ps2    = (unsigned*)(w + alc(64 * 128 * 4));
    if (o > ws_size) return;

    const int* srcOrig = ei;
    const int* dstOrig = ei + E0;

    // fused setup (x/W/pwn convert + zero bar/hist/cnt + iota), then CSR build (full-parallel)
    setupK<<<NBCVT + NBW + 1, 256, 0, stream>>>(x, xbf,
                                                Wr[0], Wroot[0], Wr[1], Wroot[1], Wr[2], Wroot[2], wbf,
                                                pw[0], pw[1], pw[2], pwn, cnt, origA, barA, hist);
    unsigned* doneA = barA + 8;   // shared self-resetting done counter
    histDstK<<<NBHD, 256, 0, stream>>>(dstOrig, cnt);
    scanRedFusedK<<<NCHUNK, 256, 0, stream>>>(cnt, chS, chO, rowptr, doneA, N0);
    scanFinalK<<<NCHUNK, 256, 0, stream>>>(cnt, cnt, chO, rowptr, N0);
    scatterFillK<<<NBHD, 256, 0, stream>>>(srcOrig, dstOrig, rowptr, cnt, sSrc0);

    const int ns[3] = { N0, KP1, KP2 };
    const int ks[3] = { KP1, KP2, KP3 };
    const int* srcCur[3] = { sSrc0, srcCA, srcCB };
    int* srcNext[3] = { srcCA, srcCB, srcCA };
    const int* origCur[3] = { origA, origB, origA };
    int* origNext[3] = { origB, origA, origB };

    for (int L = 0; L < 3; L++) {
        int n = ns[L], k = ks[L];
        const unsigned short* xinbf = (L == 0) ? xbf : bufBbf;
        int doNext = (L < 2) ? 1 : 0;

        aggSegB<<<(n + 15) / 16, 256, 0, stream>>>(xinbf, srcCur[L], rowptr, origCur[L], aggbf, n);
        int nbc = (n + 127) / 128;
        convM<<<nbc, 256, 0, stream>>>(aggbf, xinbf,
                                       wbf + (size_t)(L * 2) * 16384,
                                       wbf + (size_t)(L * 2 + 1) * 16384,
                                       br[L], pwn + L * 128, hbf, sc, keys,
                                       hist, st, doneA, n, k, nbc);
        int nbh = (n + 255) / 256;
        for (int p = 1; p < 4; p++)
            histSelK<<<nbh, 256, 0, stream>>>(keys, n, p, st, hist, doneA, nbh);
        int nb = (n + 1023) / 1024;
        countsK<<<nb, 256, 0, stream>>>(keys, n, st, bGT, bEQ, sGT, sEQ, doneA, nb);
        markOrigK<<<nb, 256, 0, stream>>>(keys, n, st, sGT, sEQ, nidx, origCur[L], origNext[L], doNext);
        int nbg = (n + 15) / 16;
        gatherRK<<<nbg, 256, 0, stream>>>(hbf, sc, nidx, srcCur[L], srcNext[L], bufBbf, pmax, psum, n, doNext);
        rfinal2K<<<64, 128, 0, stream>>>(pmax, psum, pm2, ps2, r, doneA, nbg, k, (L == 0) ? 1 : 0);
    }

    mlpK<<<1, 256, 0, stream>>>(r, W1, b1, W2, b2, W3, b3, out);
}

// Round 21
// 618.346 us; speedup vs baseline: 1.0522x; 1.0522x over previous
//
#include <hip/hip_runtime.h>
#include <hip/hip_bf16.h>
#include <math.h>

#define N0 100000
#define E0 600000
#define KP1 80000
#define KP2 64000
#define KP3 51200
#define F 128
#define SCAN_CHUNK 1024
#define NCHUNK ((N0 + SCAN_CHUNK - 1) / SCAN_CHUNK)
#define MAXGB 6400

typedef __attribute__((ext_vector_type(8))) short short8;
typedef __attribute__((ext_vector_type(8))) unsigned short ushort8;
typedef __attribute__((ext_vector_type(4))) float f32x4;

// ---------- helpers ----------
__device__ __forceinline__ unsigned fkey(float f) {
    unsigned u = __float_as_uint(f);
    return u ^ ((u & 0x80000000u) ? 0xFFFFFFFFu : 0x80000000u);
}
__device__ __forceinline__ unsigned short f2b(float f) {
    __hip_bfloat16 h = __float2bfloat16(f);
    return *(unsigned short*)&h;
}
__device__ __forceinline__ float b2f(unsigned short u) {
    __hip_bfloat16 h;
    *(unsigned short*)&h = u;
    return __bfloat162float(h);
}

// ---------- conversions; also zeroes done slots + hist + cnt, writes iota ----------
__global__ __launch_bounds__(256) void cvt4K(const float* __restrict__ in,
                                             unsigned short* __restrict__ out, int n4,
                                             unsigned* __restrict__ bar, unsigned* __restrict__ hist,
                                             unsigned* __restrict__ cnt, int* __restrict__ orig) {
    int i = blockIdx.x * 256 + threadIdx.x;
    if (blockIdx.x == 0) {
        if (threadIdx.x < 16) bar[threadIdx.x] = 0u;
        hist[threadIdx.x] = 0u;
    }
    if (i < N0) { cnt[i] = 0u; orig[i] = i; }
    if (i >= n4) return;
    float4 v = *(const float4*)(in + (size_t)i * 4);
    *(ushort4*)(out + (size_t)i * 4) = make_ushort4(f2b(v.x), f2b(v.y), f2b(v.z), f2b(v.w));
}

__global__ __launch_bounds__(256) void cvtWAllK(const float* __restrict__ a0, const float* __restrict__ a1,
                                                const float* __restrict__ a2, const float* __restrict__ a3,
                                                const float* __restrict__ a4, const float* __restrict__ a5,
                                                unsigned short* __restrict__ o) {
    int m = blockIdx.y;
    const float* src = (m == 0) ? a0 : (m == 1) ? a1 : (m == 2) ? a2 : (m == 3) ? a3 : (m == 4) ? a4 : a5;
    int i = blockIdx.x * 256 + threadIdx.x;
    float4 v = *(const float4*)(src + (size_t)i * 4);
    *(ushort4*)(o + (size_t)m * 16384 + (size_t)i * 4) = make_ushort4(f2b(v.x), f2b(v.y), f2b(v.z), f2b(v.w));
}

__global__ __launch_bounds__(128) void pwnK(const float* __restrict__ p0, const float* __restrict__ p1,
                                            const float* __restrict__ p2, float* __restrict__ pwn) {
    __shared__ float sh[128];
    int l = blockIdx.x, t = threadIdx.x;
    const float* p = (l == 0) ? p0 : (l == 1) ? p1 : p2;
    float v = p[t];
    sh[t] = v * v;
    __syncthreads();
    for (int off = 64; off; off >>= 1) {
        if (t < off) sh[t] += sh[t + off];
        __syncthreads();
    }
    pwn[l * 128 + t] = v / sqrtf(sh[0]);
}

// ---------- CSR build: full-parallel split kernels (proven R6/R7/R12) ----------
__global__ __launch_bounds__(256) void histDstK(const int* __restrict__ dst, unsigned* __restrict__ cnt) {
    int e = blockIdx.x * 256 + threadIdx.x;
    if (e < E0) atomicAdd(&cnt[dst[e]], 1u);
}

__global__ __launch_bounds__(256) void scanReduceK(const unsigned* __restrict__ cnt,
                                                   unsigned* __restrict__ chunkSum, int nbins) {
    __shared__ unsigned sh[256];
    int base = blockIdx.x * SCAN_CHUNK + threadIdx.x * 4;
    unsigned s = 0;
#pragma unroll
    for (int i = 0; i < 4; i++) { int b = base + i; if (b < nbins) s += cnt[b]; }
    sh[threadIdx.x] = s;
    __syncthreads();
    for (int off = 128; off; off >>= 1) {
        if (threadIdx.x < off) sh[threadIdx.x] += sh[threadIdx.x + off];
        __syncthreads();
    }
    if (threadIdx.x == 0) chunkSum[blockIdx.x] = sh[0];
}

__global__ void scanChunksK(const unsigned* __restrict__ chunkSum, unsigned* __restrict__ chunkOff,
                            int nchunks, unsigned* __restrict__ totalOut) {
    if (threadIdx.x == 0) {
        unsigned run = 0;
        for (int i = 0; i < nchunks; i++) { chunkOff[i] = run; run += chunkSum[i]; }
        *totalOut = run;
    }
}

__global__ __launch_bounds__(256) void scanFinalK(const unsigned* __restrict__ cntIn,
                                                  unsigned* __restrict__ cnt,   // same buf; re-zeroed
                                                  const unsigned* __restrict__ chunkOff,
                                                  unsigned* __restrict__ rowptr, int nbins) {
    __shared__ unsigned sh[256];
    int t = threadIdx.x;
    int base = blockIdx.x * SCAN_CHUNK + t * 4;
    unsigned c[4], s = 0;
#pragma unroll
    for (int i = 0; i < 4; i++) { int b = base + i; c[i] = (b < nbins) ? cntIn[b] : 0u; s += c[i]; }
    sh[t] = s;
    __syncthreads();
    for (int off = 1; off < 256; off <<= 1) {
        unsigned v = (t >= off) ? sh[t - off] : 0u;
        __syncthreads();
        sh[t] += v;
        __syncthreads();
    }
    unsigned basep = chunkOff[blockIdx.x] + sh[t] - s;
#pragma unroll
    for (int i = 0; i < 4; i++) {
        int b = base + i;
        if (b < nbins) { rowptr[b] = basep; basep += c[i]; cnt[b] = 0u; }
    }
}

__global__ __launch_bounds__(256) void scatterFillK(const int* __restrict__ src,
                                                    const int* __restrict__ dst,
                                                    const unsigned* __restrict__ rowptr,
                                                    unsigned* __restrict__ fill,
                                                    int* __restrict__ sortedSrc) {
    int e = blockIdx.x * 256 + threadIdx.x;
    if (e >= E0) return;
    int d = dst[e];
    unsigned p = rowptr[d] + atomicAdd(&fill[d], 1u);
    sortedSrc[p] = src[e];
}

// ---------- segmented aggregation (proven R7) ----------
__global__ __launch_bounds__(256) void aggSegB(const unsigned short* __restrict__ x,
                                               const int* __restrict__ srcCur,
                                               const unsigned* __restrict__ rowptr,
                                               const int* __restrict__ orig,
                                               unsigned short* __restrict__ agg, int n) {
    int g = blockIdx.x * 16 + (threadIdx.x >> 4);
    int q = threadIdx.x & 15;
    if (g >= n) return;
    int d = orig[g];
    unsigned e0 = rowptr[d], e1 = rowptr[d + 1];
    float a[8];
#pragma unroll
    for (int j = 0; j < 8; j++) a[j] = 0.f;
    unsigned e = e0;
    for (; e + 4 <= e1; e += 4) {
        int s0 = srcCur[e], s1 = srcCur[e + 1], s2 = srcCur[e + 2], s3 = srcCur[e + 3];
        ushort8 v0 = *(const ushort8*)(x + (size_t)(s0 < 0 ? 0 : s0) * F + q * 8);
        ushort8 v1 = *(const ushort8*)(x + (size_t)(s1 < 0 ? 0 : s1) * F + q * 8);
        ushort8 v2 = *(const ushort8*)(x + (size_t)(s2 < 0 ? 0 : s2) * F + q * 8);
        ushort8 v3 = *(const ushort8*)(x + (size_t)(s3 < 0 ? 0 : s3) * F + q * 8);
        float m0 = s0 < 0 ? 0.f : 1.f, m1 = s1 < 0 ? 0.f : 1.f;
        float m2 = s2 < 0 ? 0.f : 1.f, m3 = s3 < 0 ? 0.f : 1.f;
#pragma unroll
        for (int j = 0; j < 8; j++) {
            a[j] = fmaf(b2f(v0[j]), m0, a[j]);
            a[j] = fmaf(b2f(v1[j]), m1, a[j]);
            a[j] = fmaf(b2f(v2[j]), m2, a[j]);
            a[j] = fmaf(b2f(v3[j]), m3, a[j]);
        }
    }
    for (; e < e1; e++) {
        int s = srcCur[e];
        if (s < 0) continue;
        ushort8 v = *(const ushort8*)(x + (size_t)s * F + q * 8);
#pragma unroll
        for (int j = 0; j < 8; j++) a[j] += b2f(v[j]);
    }
    ushort8 o;
#pragma unroll
    for (int j = 0; j < 8; j++) o[j] = f2b(a[j]);
    *(ushort8*)(agg + (size_t)g * F + q * 8) = o;
}

// ---------- MFMA conv + score + fused radix pass 0 (R12/R15 proven-best) ----------
#define CPAD 40
__global__ __launch_bounds__(256) void convM(const unsigned short* __restrict__ A0,
                                             const unsigned short* __restrict__ A1,
                                             const unsigned short* __restrict__ W0,
                                             const unsigned short* __restrict__ W1,
                                             const float* __restrict__ br,
                                             const float* __restrict__ pwn,
                                             unsigned short* __restrict__ hbf,
                                             float* __restrict__ sc,
                                             unsigned* __restrict__ keys,
                                             unsigned* __restrict__ hist,
                                             unsigned* __restrict__ st,
                                             unsigned* __restrict__ done,
                                             int n, int k, int nbGrid) {
    __shared__ unsigned short As[128 * CPAD];
    __shared__ unsigned short Bs[128 * CPAD];
    __shared__ unsigned selh[256];
    int tid = threadIdx.x;
    int w = tid >> 6, l = tid & 63;
    int r = l & 15, g = l >> 4;
    int bm = blockIdx.x * 128;
    int srow = tid >> 2, q4 = tid & 3;

    selh[tid] = 0u;

    f32x4 acc[2][8];
#pragma unroll
    for (int m = 0; m < 2; m++)
#pragma unroll
        for (int c = 0; c < 8; c++) acc[m][c] = (f32x4){0.f, 0.f, 0.f, 0.f};

    for (int ph = 0; ph < 2; ph++) {
        const unsigned short* A = ph ? A1 : A0;
        const unsigned short* W = ph ? W1 : W0;
        for (int kk = 0; kk < 128; kk += 32) {
            __syncthreads();
#pragma unroll
            for (int h2 = 0; h2 < 2; h2++) {
                int rr = srow + h2 * 64;
                uint4 av = make_uint4(0u, 0u, 0u, 0u);
                if (bm + rr < n) av = *(const uint4*)(A + (size_t)(bm + rr) * F + kk + q4 * 8);
                *(uint4*)(&As[rr * CPAD + q4 * 8]) = av;
                uint4 wv = *(const uint4*)(W + (size_t)rr * F + kk + q4 * 8);
                *(uint4*)(&Bs[rr * CPAD + q4 * 8]) = wv;
            }
            __syncthreads();
            short8 af[2], bf[8];
#pragma unroll
            for (int m = 0; m < 2; m++)
                af[m] = *(const short8*)(&As[(w * 32 + m * 16 + r) * CPAD + g * 8]);
#pragma unroll
            for (int c = 0; c < 8; c++)
                bf[c] = *(const short8*)(&Bs[(c * 16 + r) * CPAD + g * 8]);
#pragma unroll
            for (int m = 0; m < 2; m++)
#pragma unroll
                for (int c = 0; c < 8; c++)
                    acc[m][c] = __builtin_amdgcn_mfma_f32_16x16x32_bf16(af[m], bf[c], acc[m][c], 0, 0, 0);
        }
    }

    float pd[2][4];
#pragma unroll
    for (int m = 0; m < 2; m++)
#pragma unroll
        for (int j = 0; j < 4; j++) pd[m][j] = 0.f;

#pragma unroll
    for (int c = 0; c < 8; c++) {
        int col = c * 16 + r;
        float bias = br[col];
        float pwc = pwn[col];
#pragma unroll
        for (int m = 0; m < 2; m++) {
#pragma unroll
            for (int j = 0; j < 4; j++) {
                int row = bm + w * 32 + m * 16 + g * 4 + j;
                float h = fmaxf(acc[m][c][j] + bias, 0.f);
                pd[m][j] += h * pwc;
                if (row < n) hbf[(size_t)row * F + col] = f2b(h);
            }
        }
    }
#pragma unroll
    for (int m = 0; m < 2; m++) {
#pragma unroll
        for (int j = 0; j < 4; j++) {
            float p = pd[m][j];
            p += __shfl_xor(p, 1);
            p += __shfl_xor(p, 2);
            p += __shfl_xor(p, 4);
            p += __shfl_xor(p, 8);
            if (r == 0) {
                int row = bm + w * 32 + m * 16 + g * 4 + j;
                if (row < n) {
                    float s = tanhf(p);
                    sc[row] = s;
                    unsigned key = fkey(s);
                    keys[row] = key;
                    atomicAdd(&selh[key >> 24], 1u);
                }
            }
        }
    }

    __syncthreads();
    if (selh[tid]) atomicAdd(&hist[tid], selh[tid]);
    __syncthreads();
    __shared__ bool lastS;
    if (tid == 0) {
        __threadfence();
        lastS = (atomicAdd(done, 1u) == (unsigned)(nbGrid - 1));
    }
    __syncthreads();
    if (!lastS) return;
    selh[tid] = atomicExch(&hist[tid], 0u);
    __syncthreads();
    if (tid == 0) {
        unsigned krem = (unsigned)k, cum = 0, pfx = 0;
        for (int bch = 255; bch >= 0; bch--) {
            unsigned cc = selh[bch];
            if (cum + cc >= krem) {
                pfx = ((unsigned)bch) << 24;
                krem -= cum;
                break;
            }
            cum += cc;
        }
        atomicExch(&st[0], pfx);
        atomicExch(&st[1], krem);
        *done = 0u;
    }
}

// ---------- radix passes 1..3 (proven R7/R15) ----------
__global__ __launch_bounds__(256) void histSelK(const unsigned* __restrict__ keys, int n,
                                                int p, unsigned* __restrict__ st,
                                                unsigned* __restrict__ hist,
                                                unsigned* __restrict__ done, int nb) {
    __shared__ unsigned lh[256];
    __shared__ bool last;
    int tid = threadIdx.x;
    lh[tid] = 0;
    __syncthreads();
    unsigned prefix = st[0];
    int i = blockIdx.x * 256 + tid;
    if (i < n) {
        unsigned key = keys[i];
        bool m = ((key >> (32 - 8 * p)) == (prefix >> (32 - 8 * p)));
        if (m) atomicAdd(&lh[(key >> (24 - 8 * p)) & 255u], 1u);
    }
    __syncthreads();
    if (lh[tid]) atomicAdd(&hist[tid], lh[tid]);
    __syncthreads();
    if (tid == 0) {
        __threadfence();
        last = (atomicAdd(done, 1u) == (unsigned)(nb - 1));
    }
    __syncthreads();
    if (!last) return;
    lh[tid] = atomicExch(&hist[tid], 0u);
    __syncthreads();
    if (tid == 0) {
        unsigned krem = st[1], cum = 0;
        for (int b = 255; b >= 0; b--) {
            unsigned c = lh[b];
            if (cum + c >= krem) {
                st[0] |= ((unsigned)b) << (24 - 8 * p);
                st[1] = krem - cum;
                break;
            }
            cum += c;
        }
        *done = 0u;
    }
}

// ---------- counts + fused scan (proven R13/R15) ----------
__global__ __launch_bounds__(256) void countsK(const unsigned* __restrict__ keys, int n,
                                               const unsigned* __restrict__ st,
                                               unsigned* __restrict__ bGT, unsigned* __restrict__ bEQ,
                                               unsigned* __restrict__ sGT, unsigned* __restrict__ sEQ,
                                               unsigned* __restrict__ done, int nb) {
    __shared__ int cg_, ce_;
    __shared__ bool last;
    __shared__ unsigned sgl[128], seq[128];
    int tid = threadIdx.x;
    if (tid == 0) { cg_ = 0; ce_ = 0; }
    __syncthreads();
    unsigned t = st[0];
    int g = 0, e = 0;
    for (int it = 0; it < 4; it++) {
        int i = blockIdx.x * 1024 + it * 256 + tid;
        if (i < n) {
            unsigned k = keys[i];
            g += (k > t);
            e += (k == t);
        }
    }
    atomicAdd(&cg_, g);
    atomicAdd(&ce_, e);
    __syncthreads();
    if (tid == 0) {
        bGT[blockIdx.x] = (unsigned)cg_;
        bEQ[blockIdx.x] = (unsigned)ce_;
        __threadfence();
        last = (atomicAdd(done, 1u) == (unsigned)(nb - 1));
    }
    __syncthreads();
    if (!last) return;
    if (tid < nb && tid < 128) { sgl[tid] = atomicAdd(&bGT[tid], 0u); seq[tid] = atomicAdd(&bEQ[tid], 0u); }
    __syncthreads();
    if (tid == 0) {
        unsigned gs = 0, es = 0;
        for (int b = 0; b < nb; b++) {
            atomicExch(&sGT[b], gs);
            atomicExch(&sEQ[b], es);
            gs += sgl[b];
            es += seq[b];
        }
        *done = 0u;
    }
}

// ---------- mark + buildOrig (proven R8/R11/R15) ----------
__global__ __launch_bounds__(256) void markOrigK(const unsigned* __restrict__ keys, int n,
                                                 const unsigned* __restrict__ st,
                                                 const unsigned* __restrict__ sGT,
                                                 const unsigned* __restrict__ sEQ,
                                                 int* __restrict__ nidx,
                                                 const int* __restrict__ origIn,
                                                 int* __restrict__ origOut, int doNext) {
    __shared__ int wG[4], wE[4];
    __shared__ int runG, runE;
    int tid = threadIdx.x, wv = tid >> 6, lane = tid & 63;
    if (tid == 0) { runG = 0; runE = 0; }
    unsigned t = st[0];
    int needEq = (int)st[1];
    int gOff = (int)atomicAdd((unsigned*)&sGT[blockIdx.x], 0u);
    int eOff = (int)atomicAdd((unsigned*)&sEQ[blockIdx.x], 0u);
    unsigned long long mlt = (((unsigned long long)1) << lane) - 1ull;
    __syncthreads();
    for (int it = 0; it < 4; it++) {
        int i = blockIdx.x * 1024 + it * 256 + tid;
        bool inb = i < n;
        unsigned k = inb ? keys[i] : 0u;
        bool pG = inb && (k > t), pE = inb && (k == t);
        unsigned long long bG = __ballot(pG), bE = __ballot(pE);
        int lpG = __popcll(bG & mlt), lpE = __popcll(bE & mlt);
        if (lane == 0) { wG[wv] = __popcll(bG); wE[wv] = __popcll(bE); }
        __syncthreads();
        int woG = 0, woE = 0;
        for (int w = 0; w < wv; w++) { woG += wG[w]; woE += wE[w]; }
        int gB = gOff + runG + woG + lpG;
        int eB = eOff + runE + woE + lpE;
        int ni = -1;
        if (pG) ni = gB + (eB < needEq ? eB : needEq);
        else if (pE && eB < needEq) ni = gB + eB;
        if (inb) {
            nidx[i] = ni;
            if (doNext && ni >= 0) origOut[ni] = origIn[i];
        }
        __syncthreads();
        if (tid == 0) {
            runG += wG[0] + wG[1] + wG[2] + wG[3];
            runE += wE[0] + wE[1] + wE[2] + wE[3];
        }
        __syncthreads();
    }
}

// ---------- gather + remap + readout partials (proven R11) ----------
__global__ __launch_bounds__(256) void gatherRK(const unsigned short* __restrict__ hbf,
                                                const float* __restrict__ sc,
                                                const int* __restrict__ nidx,
                                                const int* __restrict__ srcIn,
                                                int* __restrict__ srcOut,
                                                unsigned short* __restrict__ bufB,
                                                float* __restrict__ pmax, float* __restrict__ psum,
                                                int n, int doNext) {
    __shared__ float redm[256 * 8];
    __shared__ float reds[256 * 8];
    int tid = threadIdx.x, b = blockIdx.x;
    int q = tid & 15;
    int i = b * 16 + (tid >> 4);
    float lm[8], ls[8];
#pragma unroll
    for (int j = 0; j < 8; j++) { lm[j] = -INFINITY; ls[j] = 0.f; }
    if (i < n) {
        int ni = nidx[i];
        if (ni >= 0) {
            float s = sc[i];
            ushort8 v = *(const ushort8*)(hbf + (size_t)i * F + q * 8);
            ushort8 o;
#pragma unroll
            for (int j = 0; j < 8; j++) {
                float prod = b2f(v[j]) * s;
                o[j] = f2b(prod);
                lm[j] = fmaxf(lm[j], prod);
                ls[j] += prod;
            }
            *(ushort8*)(bufB + (size_t)ni * F + q * 8) = o;
        }
    }
    if (doNext) {
        int nbg = gridDim.x;
        for (int e = b * 256 + tid; e < E0; e += nbg * 256) {
            int s2 = srcIn[e];
            srcOut[e] = (s2 >= 0) ? nidx[s2] : -1;
        }
    }
#pragma unroll
    for (int j = 0; j < 8; j++) { redm[tid * 8 + j] = lm[j]; reds[tid * 8 + j] = ls[j]; }
    __syncthreads();
    if (tid < 16) {
        for (int g2 = 1; g2 < 16; g2++) {
#pragma unroll
            for (int j = 0; j < 8; j++) {
                lm[j] = fmaxf(lm[j], redm[(g2 * 16 + tid) * 8 + j]);
                ls[j] += reds[(g2 * 16 + tid) * 8 + j];
            }
        }
#pragma unroll
        for (int j = 0; j < 8; j++) {
            pmax[(size_t)b * 128 + tid * 8 + j] = lm[j];
            psum[(size_t)b * 128 + tid * 8 + j] = ls[j];
        }
    }
}

// ---------- 2-stage readout final (proven R11/R13) ----------
__global__ __launch_bounds__(128) void rfinal2K(const float* __restrict__ pmax,
                                                const float* __restrict__ psum,
                                                unsigned* __restrict__ pm2, unsigned* __restrict__ ps2,
                                                float* __restrict__ r, unsigned* __restrict__ done,
                                                int np, int k, int initR) {
    int t = threadIdx.x, b = blockIdx.x;
    float m = -INFINITY, s = 0.f;
    for (int row = b; row < np; row += 64) {
        m = fmaxf(m, pmax[(size_t)row * 128 + t]);
        s += psum[(size_t)row * 128 + t];
    }
    atomicExch(&pm2[b * 128 + t], __float_as_uint(m));
    atomicExch(&ps2[b * 128 + t], __float_as_uint(s));
    __syncthreads();
    __shared__ bool last;
    if (t == 0) {
        __threadfence();
        last = (atomicAdd(done, 1u) == 63u);
    }
    __syncthreads();
    if (!last) return;
    m = -INFINITY; s = 0.f;
#pragma unroll 8
    for (int bb = 0; bb < 64; bb++) {
        m = fmaxf(m, __uint_as_float(atomicAdd(&pm2[bb * 128 + t], 0u)));
        s += __uint_as_float(atomicAdd(&ps2[bb * 128 + t], 0u));
    }
    if (initR) { r[t] = m; r[128 + t] = s / (float)k; }
    else       { r[t] += m; r[128 + t] += s / (float)k; }
    if (t == 0) *done = 0u;
}

// ---------- final MLP ----------
__global__ __launch_bounds__(256) void mlpK(const float* __restrict__ r,
                                            const float* __restrict__ W1, const float* __restrict__ b1,
                                            const float* __restrict__ W2, const float* __restrict__ b2,
                                            const float* __restrict__ W3, const float* __restrict__ b3,
                                            float* __restrict__ out) {
    __shared__ float z0[256], z1[128], z2[64];
    int t = threadIdx.x;
    z0[t] = r[t];
    __syncthreads();
    if (t < 128) {
        float a = b1[t];
        for (int kk = 0; kk < 256; kk++) a = fmaf(W1[t * 256 + kk], z0[kk], a);
        z1[t] = fmaxf(a, 0.f);
    }
    __syncthreads();
    if (t < 64) {
        float a = b2[t];
        for (int kk = 0; kk < 128; kk++) a = fmaf(W2[t * 128 + kk], z1[kk], a);
        z2[t] = fmaxf(a, 0.f);
    }
    __syncthreads();
    if (t < 2) {
        float a = b3[t];
        for (int kk = 0; kk < 64; kk++) a = fmaf(W3[t * 64 + kk], z2[kk], a);
        out[t] = a;
    }
}

extern "C" void kernel_launch(void* const* d_in, const int* in_sizes, int n_in,
                              void* d_out, int out_size, void* d_ws, size_t ws_size,
                              hipStream_t stream) {
    const float* x = (const float*)d_in[0];
    const int* ei = (const int*)d_in[1];
    const float* Wr[3]    = { (const float*)d_in[2],  (const float*)d_in[6],  (const float*)d_in[10] };
    const float* br[3]    = { (const float*)d_in[3],  (const float*)d_in[7],  (const float*)d_in[11] };
    const float* Wroot[3] = { (const float*)d_in[4],  (const float*)d_in[8],  (const float*)d_in[12] };
    const float* pw[3]    = { (const float*)d_in[5],  (const float*)d_in[9],  (const float*)d_in[13] };
    const float* W1 = (const float*)d_in[14];
    const float* b1 = (const float*)d_in[15];
    const float* W2 = (const float*)d_in[16];
    const float* b2 = (const float*)d_in[17];
    const float* W3 = (const float*)d_in[18];
    const float* b3 = (const float*)d_in[19];
    float* out = (float*)d_out;
    char* w = (char*)d_ws;

    size_t o = 0;
    auto alc = [&](size_t bytes) { size_t r = o; o += (bytes + 255) & ~(size_t)255; return r; };
    unsigned short* hbf    = (unsigned short*)(w + alc((size_t)N0 * F * 2));
    unsigned short* xbf    = (unsigned short*)(w + alc((size_t)N0 * F * 2));
    unsigned short* aggbf  = (unsigned short*)(w + alc((size_t)N0 * F * 2));
    unsigned short* bufBbf = (unsigned short*)(w + alc((size_t)KP1 * F * 2));
    unsigned short* wbf    = (unsigned short*)(w + alc((size_t)6 * 16384 * 2));
    float*    pwn    = (float*)(w + alc(3 * 128 * 4));
    float*    sc     = (float*)(w + alc((size_t)N0 * 4));
    unsigned* keys   = (unsigned*)(w + alc((size_t)N0 * 4));
    int*      nidx   = (int*)(w + alc((size_t)N0 * 4));
    int*      sSrc0  = (int*)(w + alc((size_t)E0 * 4));
    int*      srcCA  = (int*)(w + alc((size_t)E0 * 4));
    int*      srcCB  = (int*)(w + alc((size_t)E0 * 4));
    unsigned* cnt    = (unsigned*)(w + alc((size_t)N0 * 4));
    unsigned* rowptr = (unsigned*)(w + alc((size_t)(N0 + 1) * 4));
    int*      origA  = (int*)(w + alc((size_t)N0 * 4));
    int*      origB  = (int*)(w + alc((size_t)N0 * 4));
    unsigned* chS    = (unsigned*)(w + alc(NCHUNK * 4));
    unsigned* chO    = (unsigned*)(w + alc(NCHUNK * 4));
    unsigned* hist   = (unsigned*)(w + alc(256 * 4));
    unsigned* st     = (unsigned*)(w + alc(64));
    unsigned* barA   = (unsigned*)(w + alc(16 * 4));
    unsigned* bGT    = (unsigned*)(w + alc(128 * 4));
    unsigned* bEQ    = (unsigned*)(w + alc(128 * 4));
    unsigned* sGT    = (unsigned*)(w + alc(128 * 4));
    unsigned* sEQ    = (unsigned*)(w + alc(128 * 4));
    float*    r      = (float*)(w + alc(256 * 4));
    float*    pmax   = (float*)(w + alc((size_t)MAXGB * F * 4));
    float*    psum   = (float*)(w + alc((size_t)MAXGB * F * 4));
    unsigned* pm2    = (unsigned*)(w + alc(64 * 128 * 4));
    unsigned* ps2    = (unsigned*)(w + alc(64 * 128 * 4));
    if (o > ws_size) return;

    const int* srcOrig = ei;
    const int* dstOrig = ei + E0;

    // setup: conversions (cvt4K zeroes barA/hist/cnt + iota origA), CSR build (full-parallel split)
    cvt4K<<<(N0 * F / 4 + 255) / 256, 256, 0, stream>>>(x, xbf, N0 * F / 4, barA, hist, cnt, origA);
    cvtWAllK<<<dim3(16, 6), 256, 0, stream>>>(Wr[0], Wroot[0], Wr[1], Wroot[1], Wr[2], Wroot[2], wbf);
    pwnK<<<3, 128, 0, stream>>>(pw[0], pw[1], pw[2], pwn);
    histDstK<<<(E0 + 255) / 256, 256, 0, stream>>>(dstOrig, cnt);
    scanReduceK<<<NCHUNK, 256, 0, stream>>>(cnt, chS, N0);
    scanChunksK<<<1, 1, 0, stream>>>(chS, chO, NCHUNK, rowptr + N0);
    scanFinalK<<<NCHUNK, 256, 0, stream>>>(cnt, cnt, chO, rowptr, N0);
    scatterFillK<<<(E0 + 255) / 256, 256, 0, stream>>>(srcOrig, dstOrig, rowptr, cnt, sSrc0);

    unsigned* doneA = barA + 8;   // shared self-resetting done counter

    const int ns[3] = { N0, KP1, KP2 };
    const int ks[3] = { KP1, KP2, KP3 };
    const int* srcCur[3] = { sSrc0, srcCA, srcCB };
    int* srcNext[3] = { srcCA, srcCB, srcCA };
    const int* origCur[3] = { origA, origB, origA };
    int* origNext[3] = { origB, origA, origB };

    for (int L = 0; L < 3; L++) {
        int n = ns[L], k = ks[L];
        const unsigned short* xinbf = (L == 0) ? xbf : bufBbf;
        int doNext = (L < 2) ? 1 : 0;

        aggSegB<<<(n + 15) / 16, 256, 0, stream>>>(xinbf, srcCur[L], rowptr, origCur[L], aggbf, n);
        int nbc = (n + 127) / 128;
        convM<<<nbc, 256, 0, stream>>>(aggbf, xinbf,
                                       wbf + (size_t)(L * 2) * 16384,
                                       wbf + (size_t)(L * 2 + 1) * 16384,
                                       br[L], pwn + L * 128, hbf, sc, keys,
                                       hist, st, doneA, n, k, nbc);
        int nbh = (n + 255) / 256;
        for (int p = 1; p < 4; p++)
            histSelK<<<nbh, 256, 0, stream>>>(keys, n, p, st, hist, doneA, nbh);
        int nb = (n + 1023) / 1024;
        countsK<<<nb, 256, 0, stream>>>(keys, n, st, bGT, bEQ, sGT, sEQ, doneA, nb);
        markOrigK<<<nb, 256, 0, stream>>>(keys, n, st, sGT, sEQ, nidx, origCur[L], origNext[L], doNext);
        int nbg = (n + 15) / 16;
        gatherRK<<<nbg, 256, 0, stream>>>(hbf, sc, nidx, srcCur[L], srcNext[L], bufBbf, pmax, psum, n, doNext);
        rfinal2K<<<64, 128, 0, stream>>>(pmax, psum, pm2, ps2, r, doneA, nbg, k, (L == 0) ? 1 : 0);
    }

    mlpK<<<1, 256, 0, stream>>>(r, W1, b1, W2, b2, W3, b3, out);
}